// Round 1
// baseline (144.676 us; speedup 1.0000x reference)
//
#include <hip/hip_runtime.h>
#include <math.h>

#define N 2048
#define D 64
#define KP 4
#define BT 128   // edge_kernel tile (BT x BT per block)

// tanh(x) for x>0 via one exp:  tanh(x) = 1 - 2/(e^{2x}+1)
__device__ __forceinline__ float tanh_pos(float x) {
  return 1.0f - 2.0f / (expf(2.0f * x) + 1.0f);
}

// ---------------- Kernel 1: EA = edges @ attributes ----------------
// edges is binary; one block per row, 4 wave-groups scan the row,
// conditional adds of attribute rows (wave-uniform branch).
__global__ __launch_bounds__(256) void ea_kernel(
    const float* __restrict__ edges, const float* __restrict__ attr,
    float* __restrict__ EA)
{
  int row = blockIdx.x;
  int t = threadIdx.x;
  int d = t & 63;
  int jg = t >> 6;  // 0..3
  const float* erow = edges + (size_t)row * N;
  float acc = 0.0f;
  for (int j4 = jg * 4; j4 < N; j4 += 16) {
    float4 w = *reinterpret_cast<const float4*>(erow + j4);
    if (w.x != 0.0f) acc += attr[(j4 + 0) * D + d];
    if (w.y != 0.0f) acc += attr[(j4 + 1) * D + d];
    if (w.z != 0.0f) acc += attr[(j4 + 2) * D + d];
    if (w.w != 0.0f) acc += attr[(j4 + 3) * D + d];
  }
  __shared__ float part[4][64];
  part[jg][d] = acc;
  __syncthreads();
  if (t < 64) {
    EA[(size_t)row * D + t] = part[0][t] + part[1][t] + part[2][t] + part[3][t];
  }
}

// ---------------- Kernel 2: next_feat -> sigmoid/attr_prob, Fn ----------------
// One wave per row (4 rows per block). lane d handles dim d.
__global__ __launch_bounds__(256) void feat_kernel(
    const float* __restrict__ attr, const float* __restrict__ EA,
    const float* __restrict__ persona, const int* __restrict__ timesP,
    const float* __restrict__ rp, const float* __restrict__ Wp,
    float* __restrict__ Fn, float* __restrict__ out)
{
  int t = threadIdx.x;
  int w = t >> 6, d = t & 63;
  int row = blockIdx.x * 4 + w;
  int times = timesP[0];
  float a  = attr[(size_t)row * D + d];
  float ea = EA[(size_t)row * D + d];
  float ap = 0.0f;
  #pragma unroll
  for (int i = 0; i < KP; ++i) {
    float ri = rp[i], Wi = Wp[i];
    float nf = ri * a + ea * Wi * (1.0f - ri);
    float ss = nf * nf;
    #pragma unroll
    for (int off = 32; off; off >>= 1) ss += __shfl_xor(ss, off);
    float inv = rsqrtf(ss);
    Fn[((size_t)i * N + row) * D + d] = nf * inv;
    float p = persona[((size_t)times * N + row) * KP + i];
    ap += p / (1.0f + expf(-nf));
  }
  out[(size_t)N * N + (size_t)row * D + d] = ap;
}

// ---------------- Kernel 3: edges_prob ----------------
// 128x128 tile per block; 256 threads, 8x8 micro-tile each.
// Fn tiles staged transposed in LDS with XOR swizzle:
//   value (row r, dim d) stored at AT[d][ r ^ (d & 60) ]
// -> float4 reads along r are contiguous & conflict-light.
__global__ __launch_bounds__(256) void edge_kernel(
    const float* __restrict__ edges, const float* __restrict__ two_hop,
    const float* __restrict__ persona, const int* __restrict__ timesP,
    const float* __restrict__ Tp, const float* __restrict__ ep,
    const float* __restrict__ Fn, float* __restrict__ out)
{
  __shared__ float AT[D][BT];   // row-tile, transposed+swizzled
  __shared__ float BTile[D][BT];// col-tile, transposed+swizzled

  int t  = threadIdx.x;
  int tx = t & 15;   // col group: cols 8*tx .. 8*tx+7
  int ty = t >> 4;   // row group: rows 8*ty .. 8*ty+7
  int row0 = blockIdx.y * BT;
  int col0 = blockIdx.x * BT;
  int times = timesP[0];

  // ---- masks for my 8x8 elements ----
  unsigned long long me = 0ull, mt = 0ull;
  #pragma unroll
  for (int jr = 0; jr < 8; ++jr) {
    int row = row0 + 8 * ty + jr;
    const float4* er = reinterpret_cast<const float4*>(edges   + (size_t)row * N + col0 + 8 * tx);
    const float4* tr = reinterpret_cast<const float4*>(two_hop + (size_t)row * N + col0 + 8 * tx);
    float4 e0 = er[0], e1 = er[1];
    float4 t0 = tr[0], t1 = tr[1];
    float ev[8] = {e0.x, e0.y, e0.z, e0.w, e1.x, e1.y, e1.z, e1.w};
    float tv[8] = {t0.x, t0.y, t0.z, t0.w, t1.x, t1.y, t1.z, t1.w};
    #pragma unroll
    for (int jc = 0; jc < 8; ++jc) {
      int col = col0 + 8 * tx + jc;
      unsigned long long bit = 1ull << (jr * 8 + jc);
      if (ev[jc] > 0.0f) me |= bit;
      if ((row != col) && (ev[jc] + tv[jc] > 0.0f)) mt |= bit;
    }
  }

  float acc[8][8];
  #pragma unroll
  for (int jr = 0; jr < 8; ++jr)
    #pragma unroll
    for (int jc = 0; jc < 8; ++jc) acc[jr][jc] = 0.0f;

  for (int i = 0; i < KP; ++i) {
    __syncthreads();  // previous iteration's reads done
    // ---- stage Fn tiles (transposed + swizzled) ----
    {
      int d4 = 4 * (t & 15);
      #pragma unroll
      for (int pass = 0; pass < 8; ++pass) {
        int r = (t >> 4) + 16 * pass;          // 0..127
        int ca = r ^ d4;                        // swizzled column
        float4 va = *reinterpret_cast<const float4*>(
            Fn + ((size_t)i * N + row0 + r) * D + d4);
        AT[d4 + 0][ca] = va.x;
        AT[d4 + 1][ca] = va.y;
        AT[d4 + 2][ca] = va.z;
        AT[d4 + 3][ca] = va.w;
        float4 vb = *reinterpret_cast<const float4*>(
            Fn + ((size_t)i * N + col0 + r) * D + d4);
        BTile[d4 + 0][ca] = vb.x;
        BTile[d4 + 1][ca] = vb.y;
        BTile[d4 + 2][ca] = vb.z;
        BTile[d4 + 3][ca] = vb.w;
      }
    }
    __syncthreads();

    // persona weights for my 8 columns at this i
    float pc[8];
    #pragma unroll
    for (int jc = 0; jc < 8; ++jc) {
      pc[jc] = persona[((size_t)times * N + col0 + 8 * tx + jc) * KP + i];
    }
    float invT = 1.0f / Tp[i];
    float ei = ep[i];

    // ---- S = FnRow . FnCol over d ----
    float s[8][8];
    #pragma unroll
    for (int jr = 0; jr < 8; ++jr)
      #pragma unroll
      for (int jc = 0; jc < 8; ++jc) s[jr][jc] = 0.0f;

    #pragma unroll 4
    for (int d = 0; d < D; ++d) {
      int sw = d & 60;
      float4 a0 = *reinterpret_cast<const float4*>(&AT[d][(8 * ty)     ^ sw]);
      float4 a1 = *reinterpret_cast<const float4*>(&AT[d][(8 * ty + 4) ^ sw]);
      float4 b0 = *reinterpret_cast<const float4*>(&BTile[d][(8 * tx)     ^ sw]);
      float4 b1 = *reinterpret_cast<const float4*>(&BTile[d][(8 * tx + 4) ^ sw]);
      float ar[8] = {a0.x, a0.y, a0.z, a0.w, a1.x, a1.y, a1.z, a1.w};
      float bc[8] = {b0.x, b0.y, b0.z, b0.w, b1.x, b1.y, b1.z, b1.w};
      #pragma unroll
      for (int jr = 0; jr < 8; ++jr)
        #pragma unroll
        for (int jc = 0; jc < 8; ++jc)
          s[jr][jc] += ar[jr] * bc[jc];
    }

    // ---- masked nonlinearity, accumulate ----
    #pragma unroll
    for (int jr = 0; jr < 8; ++jr) {
      #pragma unroll
      for (int jc = 0; jc < 8; ++jc) {
        unsigned long long bit = 1ull << (jr * 8 + jc);
        if (mt & bit) {
          float S = s[jr][jc];
          float v = tanh_pos(expf(S * invT) * ei);        // conn / one_conn
          if (me & bit) {
            v *= tanh_pos(expf((1.0f - S) * invT) * ei);  // * delete -> common
          }
          acc[jr][jc] += v * pc[jc];
        }
      }
    }
  }

  // ---- store ----
  #pragma unroll
  for (int jr = 0; jr < 8; ++jr) {
    int row = row0 + 8 * ty + jr;
    float4 o0 = {acc[jr][0], acc[jr][1], acc[jr][2], acc[jr][3]};
    float4 o1 = {acc[jr][4], acc[jr][5], acc[jr][6], acc[jr][7]};
    float4* dst = reinterpret_cast<float4*>(out + (size_t)row * N + col0 + 8 * tx);
    dst[0] = o0;
    dst[1] = o1;
  }
}

extern "C" void kernel_launch(void* const* d_in, const int* in_sizes, int n_in,
                              void* d_out, int out_size, void* d_ws, size_t ws_size,
                              hipStream_t stream) {
  const float* attributes = (const float*)d_in[0];
  const float* edges      = (const float*)d_in[1];
  const float* two_hop    = (const float*)d_in[2];
  const float* persona    = (const float*)d_in[3];
  const float* Tp         = (const float*)d_in[4];
  const float* ep         = (const float*)d_in[5];
  const float* rp         = (const float*)d_in[6];
  const float* Wp         = (const float*)d_in[7];
  const int*   timesP     = (const int*)d_in[8];
  float* out = (float*)d_out;

  // workspace: EA [N*D] then Fn [KP*N*D]  (total 2.625 MB)
  float* EA = (float*)d_ws;
  float* Fn = EA + (size_t)N * D;

  ea_kernel<<<N, 256, 0, stream>>>(edges, attributes, EA);
  feat_kernel<<<N / 4, 256, 0, stream>>>(attributes, EA, persona, timesP,
                                         rp, Wp, Fn, out);
  edge_kernel<<<dim3(N / BT, N / BT), 256, 0, stream>>>(
      edges, two_hop, persona, timesP, Tp, ep, Fn, out);
}

// Round 2
// 38.372 us; speedup vs baseline: 3.7704x; 3.7704x over previous
//
#include <hip/hip_runtime.h>
#include <math.h>

#define N 2048
#define D 64
#define KP 4

typedef unsigned int uint;
typedef unsigned short ushort;
typedef __attribute__((ext_vector_type(8))) short bf16x8;
typedef __attribute__((ext_vector_type(4))) float f32x4;
typedef __attribute__((ext_vector_type(4))) uint uint4v;

// float -> bf16 round-to-nearest-even
__device__ __forceinline__ ushort f2bf(float f) {
  uint u = __builtin_bit_cast(uint, f);
  u += 0x7FFFu + ((u >> 16) & 1u);
  return (ushort)(u >> 16);
}

// ---------------- Kernel 1: per-row fused EA / feat / Fn_bf16 / attr_prob --
// One block per row. Phase 1: compact nonzero edge columns to an LDS list.
// Phase 2: gather-sum attribute rows (4 waves partial). Phase 3: wave i
// computes persona-component i: next_feat, sigmoid*persona, L2-normalized
// Fn rounded to bf16.
__global__ __launch_bounds__(256) void row_kernel(
    const float* __restrict__ attr, const float* __restrict__ edges,
    const float* __restrict__ persona, const int* __restrict__ timesP,
    const float* __restrict__ rp, const float* __restrict__ Wp,
    ushort* __restrict__ Fnb, float* __restrict__ out)
{
  __shared__ int list[2048];
  __shared__ int cnt;
  __shared__ float part[4][64];

  int t = threadIdx.x;
  int w = t >> 6, d = t & 63;
  int row = blockIdx.x;

  if (t == 0) cnt = 0;
  __syncthreads();

  // phase 1: compact nonzero columns (coalesced scan, ~20 hits/row)
  const float* erow = edges + (size_t)row * N;
  for (int j = t; j < N; j += 256) {
    if (erow[j] != 0.0f) {
      int p = atomicAdd(&cnt, 1);
      list[p] = j;
    }
  }
  __syncthreads();
  int cn = cnt;

  // phase 2: EA[d] = sum over neighbors of attr[idx][d]
  float acc = 0.0f;
  for (int k = w; k < cn; k += 4) {
    acc += attr[(size_t)list[k] * D + d];
  }
  part[w][d] = acc;
  __syncthreads();
  float ea = part[0][d] + part[1][d] + part[2][d] + part[3][d];
  __syncthreads();   // before part reuse

  // phase 3: wave w handles persona component i = w
  float a = attr[(size_t)row * D + d];
  float ri = rp[w], Wi = Wp[w];
  float nf = ri * a + ea * Wi * (1.0f - ri);
  float ss = nf * nf;
  #pragma unroll
  for (int off = 32; off; off >>= 1) ss += __shfl_xor(ss, off);
  float inv = rsqrtf(ss);
  Fnb[((size_t)w * N + row) * D + d] = f2bf(nf * inv);

  int times = timesP[0];
  float p = persona[((size_t)times * N + row) * KP + w];
  float sig = 1.0f / (1.0f + __expf(-nf));
  part[w][d] = p * sig;
  __syncthreads();
  if (w == 0) {
    out[(size_t)N * N + (size_t)row * D + d] =
        part[0][d] + part[1][d] + part[2][d] + part[3][d];
  }
}

// ---------------- Kernel 2: edges_prob via bf16 MFMA ----------------
// 64x64 tile/block, 256 threads = 4 waves, wave (wr,wc) owns a 32x32
// quadrant = 2x2 tiles of 16x16, K=64 in 2 mfma steps.
// Fn panels staged to LDS bf16 with XOR swizzle: byte ^= (row&7)<<4.
__device__ __forceinline__ bf16x8 frag_read(const ushort* buf, int prow, int dbyte) {
  int off = prow * 128 + (dbyte ^ ((prow & 7) << 4));
  return *(const bf16x8*)((const char*)buf + off);
}

__global__ __launch_bounds__(256, 4) void edge_kernel(
    const float* __restrict__ edges, const float* __restrict__ two_hop,
    const float* __restrict__ persona, const int* __restrict__ timesP,
    const float* __restrict__ Tp, const float* __restrict__ ep,
    const ushort* __restrict__ Fnb, float* __restrict__ out)
{
  __shared__ ushort Ab[64 * 64];
  __shared__ ushort Bb[64 * 64];

  int t = threadIdx.x;
  int w = t >> 6, l = t & 63;
  int wr = w >> 1, wc = w & 1;
  int lr = l >> 4, lc = l & 15;
  int row0 = blockIdx.y * 64;
  int col0 = blockIdx.x * 64;
  int times = timesP[0];

  // ---- masks for my 16 elements (MFMA C/D layout) ----
  uint mem = 0, mtm = 0;
  #pragma unroll
  for (int mt_ = 0; mt_ < 2; ++mt_) {
    #pragma unroll
    for (int nt_ = 0; nt_ < 2; ++nt_) {
      #pragma unroll
      for (int j = 0; j < 4; ++j) {
        int row = row0 + wr * 32 + mt_ * 16 + lr * 4 + j;
        int col = col0 + wc * 32 + nt_ * 16 + lc;
        float ev = edges[(size_t)row * N + col];
        float tv = two_hop[(size_t)row * N + col];
        int b = (mt_ * 2 + nt_) * 4 + j;
        if (ev > 0.0f) mem |= 1u << b;
        if ((row != col) && (ev + tv > 0.0f)) mtm |= 1u << b;
      }
    }
  }

  // ---- persona for my 2 column tiles, all 4 components ----
  float pc[KP][2];
  #pragma unroll
  for (int i = 0; i < KP; ++i) {
    #pragma unroll
    for (int nt_ = 0; nt_ < 2; ++nt_) {
      int col = col0 + wc * 32 + nt_ * 16 + lc;
      pc[i][nt_] = persona[((size_t)times * N + col) * KP + i];
    }
  }

  f32x4 acc[2][2] = {};

  #pragma unroll
  for (int i = 0; i < KP; ++i) {
    __syncthreads();
    // ---- stage Fn panels (bf16, swizzled) ----
    {
      int r = t >> 2, q = t & 3;
      uint sw = (uint)((r & 7) << 4);
      const char* srcA = (const char*)(Fnb + ((size_t)i * N + row0 + r) * D);
      uint4v a0 = *(const uint4v*)(srcA + q * 32);
      uint4v a1 = *(const uint4v*)(srcA + q * 32 + 16);
      char* dstA = (char*)Ab + r * 128;
      *(uint4v*)(dstA + ((q * 32) ^ sw)) = a0;
      *(uint4v*)(dstA + ((q * 32 + 16) ^ sw)) = a1;
      const char* srcB = (const char*)(Fnb + ((size_t)i * N + col0 + r) * D);
      uint4v b0 = *(const uint4v*)(srcB + q * 32);
      uint4v b1 = *(const uint4v*)(srcB + q * 32 + 16);
      char* dstB = (char*)Bb + r * 128;
      *(uint4v*)(dstB + ((q * 32) ^ sw)) = b0;
      *(uint4v*)(dstB + ((q * 32 + 16) ^ sw)) = b1;
    }
    __syncthreads();

    // ---- S quadrant via MFMA ----
    f32x4 S[2][2] = {};
    #pragma unroll
    for (int ks = 0; ks < 2; ++ks) {
      int dbyte = ks * 64 + lr * 16;
      bf16x8 a0 = frag_read(Ab, wr * 32 + lc, dbyte);
      bf16x8 a1 = frag_read(Ab, wr * 32 + 16 + lc, dbyte);
      bf16x8 b0 = frag_read(Bb, wc * 32 + lc, dbyte);
      bf16x8 b1 = frag_read(Bb, wc * 32 + 16 + lc, dbyte);
      S[0][0] = __builtin_amdgcn_mfma_f32_16x16x32_bf16(a0, b0, S[0][0], 0, 0, 0);
      S[0][1] = __builtin_amdgcn_mfma_f32_16x16x32_bf16(a0, b1, S[0][1], 0, 0, 0);
      S[1][0] = __builtin_amdgcn_mfma_f32_16x16x32_bf16(a1, b0, S[1][0], 0, 0, 0);
      S[1][1] = __builtin_amdgcn_mfma_f32_16x16x32_bf16(a1, b1, S[1][1], 0, 0, 0);
    }

    // ---- masked nonlinearity ----
    float invT = 1.0f / Tp[i];
    float ei = ep[i];
    #pragma unroll
    for (int mt_ = 0; mt_ < 2; ++mt_) {
      #pragma unroll
      for (int nt_ = 0; nt_ < 2; ++nt_) {
        #pragma unroll
        for (int j = 0; j < 4; ++j) {
          int b = (mt_ * 2 + nt_) * 4 + j;
          if ((mtm >> b) & 1) {
            float Sv = S[mt_][nt_][j];
            float g = __expf(Sv * invT) * ei;
            float v = 1.0f - 2.0f / (__expf(2.0f * g) + 1.0f);   // tanh(g), g>0
            if ((mem >> b) & 1) {
              float g2 = __expf((1.0f - Sv) * invT) * ei;
              v *= 1.0f - 2.0f / (__expf(2.0f * g2) + 1.0f);
            }
            acc[mt_][nt_][j] += v * pc[i][nt_];
          }
        }
      }
    }
  }

  // ---- store ----
  #pragma unroll
  for (int mt_ = 0; mt_ < 2; ++mt_) {
    #pragma unroll
    for (int nt_ = 0; nt_ < 2; ++nt_) {
      #pragma unroll
      for (int j = 0; j < 4; ++j) {
        int row = row0 + wr * 32 + mt_ * 16 + lr * 4 + j;
        int col = col0 + wc * 32 + nt_ * 16 + lc;
        out[(size_t)row * N + col] = acc[mt_][nt_][j];
      }
    }
  }
}

extern "C" void kernel_launch(void* const* d_in, const int* in_sizes, int n_in,
                              void* d_out, int out_size, void* d_ws, size_t ws_size,
                              hipStream_t stream) {
  const float* attributes = (const float*)d_in[0];
  const float* edges      = (const float*)d_in[1];
  const float* two_hop    = (const float*)d_in[2];
  const float* persona    = (const float*)d_in[3];
  const float* Tp         = (const float*)d_in[4];
  const float* ep         = (const float*)d_in[5];
  const float* rp         = (const float*)d_in[6];
  const float* Wp         = (const float*)d_in[7];
  const int*   timesP     = (const int*)d_in[8];
  float* out = (float*)d_out;

  // workspace: Fn_bf16 [KP][N][D] = 1 MB
  ushort* Fnb = (ushort*)d_ws;

  row_kernel<<<N, 256, 0, stream>>>(attributes, edges, persona, timesP,
                                    rp, Wp, Fnb, out);
  edge_kernel<<<dim3(N / 64, N / 64), 256, 0, stream>>>(
      edges, two_hop, persona, timesP, Tp, ep, Fnb, out);
}